// Round 9
// baseline (213.347 us; speedup 1.0000x reference)
//
#include <hip/hip_runtime.h>
#include <hip/hip_bf16.h>

typedef unsigned short u16;
typedef __attribute__((ext_vector_type(8))) __bf16 bf16x8;
typedef __attribute__((ext_vector_type(4))) float f32x4;
typedef __attribute__((ext_vector_type(8))) u16 u16x8;

#define BATCH 2
#define SEQ   2048
#define DIM   1024
#define HEADS 16
#define HDIM  64

// 0.125 (1/sqrt(64)) * log2(e): folded into Q so attn uses bare exp2
#define QSCALE 0.18033688011112042f

__device__ __forceinline__ float bf2f(u16 u) {
  union { unsigned int u; float f; } v; v.u = ((unsigned int)u) << 16; return v.f;
}
__device__ __forceinline__ u16 f2bf(float f) {
  union { float f; unsigned int u; } v; v.f = f;
  unsigned int r = v.u + 0x7fffu + ((v.u >> 16) & 1u);
  return (u16)(r >> 16);
}
// pack two fp32 -> bf16x2 (RNE) in one HW instr (v_cvt_pk_bf16_f32)
__device__ __forceinline__ unsigned int pk2(float a, float b) {
  union { __hip_bfloat162 h2; unsigned int u; } v;
  v.h2 = __float22bfloat162_rn(float2{a, b});
  return v.u;
}

// async global->LDS DMA, 16 B per lane; LDS dest = wave-uniform base + lane*16
__device__ __forceinline__ void async16(u16* lds, const u16* g) {
  __builtin_amdgcn_global_load_lds(
      (__attribute__((address_space(1))) void*)(void*)(g),
      (__attribute__((address_space(3))) void*)(lds), 16, 0, 0);
}

// ---------------------------------------------------------------------------
// Kernel 0: one-shot fp32 -> bf16 (RNE) conversion of x, Wq, Wk, Wv.
// ---------------------------------------------------------------------------
#define XG  524288   /* x groups of 8 */
#define WG  131072   /* per-W groups of 8 */
extern "C" __global__ __launch_bounds__(256)
void convert_all(const float* __restrict__ x,  const float* __restrict__ wq,
                 const float* __restrict__ wk, const float* __restrict__ wv,
                 u16* __restrict__ xbf, u16* __restrict__ wbf)
{
  const int g = blockIdx.x * 256 + threadIdx.x;
  const float* src; u16* dst; size_t off;
  if (g < XG)               { src = x;  dst = xbf;                 off = (size_t)g; }
  else if (g < XG + WG)     { src = wq; dst = wbf;                 off = (size_t)(g - XG); }
  else if (g < XG + 2 * WG) { src = wk; dst = wbf + DIM * DIM;     off = (size_t)(g - XG - WG); }
  else                      { src = wv; dst = wbf + 2 * DIM * DIM; off = (size_t)(g - XG - 2 * WG); }
  f32x4 a = *(const f32x4*)(src + off * 8);
  f32x4 b = *(const f32x4*)(src + off * 8 + 4);
  u16x8 o;
#pragma unroll
  for (int i = 0; i < 4; ++i) { o[i] = f2bf(a[i]); o[4 + i] = f2bf(b[i]); }
  *(u16x8*)(dst + off * 8) = o;
}

// ---------------------------------------------------------------------------
// Kernel 1: QKV projection. Synchronous staging (dbuf was neutral - m99
// lesson), BK=64: halves the barrier-drain count vs BK=32. 128x128 tile,
// 4 waves x 4x4x(ks2) MFMA. LDS rows pitch 64 u16 (128B) with 16B-chunk
// XOR swizzle (chunk' = chunk ^ (row&7)) -> conflict-free b128 reads.
// grid: (8, 32, 3)  block: 256
// which==0 -> Q(*QSCALE) [b][h][s][d]; 1 -> K [b][h][s][d]; 2 -> V^T [b][h][d][s]
// ---------------------------------------------------------------------------
extern "C" __global__ __launch_bounds__(256)
void qkv_gemm(const u16* __restrict__ xbf, const u16* __restrict__ wbf,
              const float* __restrict__ bq, const float* __restrict__ bk,
              const float* __restrict__ bv,
              u16* __restrict__ qo, u16* __restrict__ ko, u16* __restrict__ vto)
{
  __shared__ alignas(16) u16 Albs[128 * 64];  // 16 KB
  __shared__ alignas(16) u16 Blbs[128 * 64];  // 16 KB

  const int which = blockIdx.z;
  const u16* Wb = wbf + (size_t)which * DIM * DIM;
  const float* bias = (which == 0) ? bq : (which == 1) ? bk : bv;

  const int lane = threadIdx.x & 63;
  const int wave = threadIdx.x >> 6;
  const int l16  = lane & 15;
  const int quad = lane >> 4;
  const int r8   = lane >> 3;       // DMA: row within 8-row group
  const int sl   = lane & 7;        // DMA: 16B slot within 128B row
  const int jsw  = sl ^ (r8 & 7);   // swizzled source chunk
  const int e7   = l16 & 7;         // read-side swizzle key

  const int mBase = blockIdx.y * 128;
  const int nBase = blockIdx.x * 128;
  const int mw = (wave >> 1) * 64;  // wave's 64x64 quadrant
  const int nw = (wave & 1) * 64;

  f32x4 acc[4][4] = {};

  for (int k0 = 0; k0 < DIM; k0 += 64) {
#pragma unroll
    for (int p = 0; p < 4; ++p) {
      const int i = wave * 4 + p;                    // 1KB chunk: rows i*8..+7
      async16(&Albs[i * 512], xbf + (size_t)(mBase + i * 8 + r8) * DIM + k0 + jsw * 8);
      async16(&Blbs[i * 512], Wb  + (size_t)(nBase + i * 8 + r8) * DIM + k0 + jsw * 8);
    }
    asm volatile("s_waitcnt vmcnt(0)" ::: "memory");
    __syncthreads();

    bf16x8 af[4][2], bfr[4][2];
#pragma unroll
    for (int i = 0; i < 4; ++i)
#pragma unroll
      for (int ks = 0; ks < 2; ++ks) {
        af[i][ks]  = *(const bf16x8*)&Albs[(mw + i * 16 + l16) * 64 + ((ks * 4 + quad) ^ e7) * 8];
        bfr[i][ks] = *(const bf16x8*)&Blbs[(nw + i * 16 + l16) * 64 + ((ks * 4 + quad) ^ e7) * 8];
      }
#pragma unroll
    for (int ks = 0; ks < 2; ++ks)
#pragma unroll
      for (int mi = 0; mi < 4; ++mi)
#pragma unroll
        for (int ni = 0; ni < 4; ++ni)
          acc[mi][ni] = __builtin_amdgcn_mfma_f32_16x16x32_bf16(af[mi][ks], bfr[ni][ks], acc[mi][ni], 0, 0, 0);
    __syncthreads();
  }

  const float oscale = (which == 0) ? QSCALE : 1.0f;
#pragma unroll
  for (int ni = 0; ni < 4; ++ni) {
    const int n = nBase + nw + ni * 16 + l16;   // C/D col = lane&15
    const float bval = bias[n];
    const int h = n >> 6, d = n & 63;
#pragma unroll
    for (int mi = 0; mi < 4; ++mi) {
#pragma unroll
      for (int r = 0; r < 4; ++r) {
        const int m = mBase + mw + mi * 16 + quad * 4 + r;  // row = quad*4+reg
        const int bi = m >> 11, s = m & 2047;
        const u16 val = f2bf((acc[mi][ni][r] + bval) * oscale);
        if (which == 2) {
          vto[((size_t)(bi * HEADS + h) * HDIM + d) * SEQ + s] = val;
        } else {
          u16* dst = (which == 0) ? qo : ko;
          dst[((size_t)(bi * HEADS + h) * SEQ + s) * HDIM + d] = val;
        }
      }
    }
  }
}

// ---------------------------------------------------------------------------
// Kernel 2: flash attention per (b, h), software-pipelined across key tiles.
// Triple-buffered K/V (prefetch distance 2); per iter: exp(t) -> QK^T(t+1)
// -> PV(t), so the MFMA pipe runs QK(t+1) while VALU does exp(t) and the P
// LDS round-trip drains. Wave owns 32 q-rows; block = 128 q-rows.
// S^T = K*Q (swapped operands) -> lane's 4 P-values are z-consecutive for
// one q-row -> packed ds_write_b64. P swizzle at 8B slots: slot' = slot ^
// 2*(s&7) (even XOR keeps 16B read pairs adjacent; writes 2x/bank = free).
// LDS = 3x8K (K) + 3x8K (V) + 16K (P) = 64 KB -> 2 blocks/CU (= grid cap).
// grid: (SEQ/128, HEADS, BATCH) = (16,16,2)  block: 256
// ---------------------------------------------------------------------------
extern "C" __global__ __launch_bounds__(256)
void attn(const u16* __restrict__ q, const u16* __restrict__ k,
          const u16* __restrict__ vt, float* __restrict__ out)
{
  __shared__ alignas(16) u16 Klds[3][64 * 64];
  __shared__ alignas(16) u16 Vlds[3][64 * 64];
  __shared__ alignas(16) u16 Plds[4][32 * 64];

  const int lane = threadIdx.x & 63;
  const int wave = threadIdx.x >> 6;
  const int l16  = lane & 15;
  const int quad = lane >> 4;
  const int r8   = lane >> 3;       // DMA: row within 8-row group
  const int sl   = lane & 7;        // DMA: 16B slot within row
  const int jsw  = sl ^ (r8 & 7);   // swizzled source chunk for DMA
  const int e7   = l16 & 7;         // 16B-chunk swizzle key (K/V reads)
  const int psw  = e7 * 2;          // 8B-slot swizzle key (P)

  const int h     = blockIdx.y;
  const int b     = blockIdx.z;
  const int qbase = blockIdx.x * 128 + wave * 32;

  const u16* qh  = q  + (size_t)(b * HEADS + h) * SEQ * HDIM;
  const u16* kh  = k  + (size_t)(b * HEADS + h) * SEQ * HDIM;
  const u16* vth = vt + (size_t)(b * HEADS + h) * HDIM * SEQ;

  // Q B-frags: lane l16 -> q-row qbase+qg*16+l16, k = ks*32+quad*8..+7
  bf16x8 qf[2][2];
#pragma unroll
  for (int qg = 0; qg < 2; ++qg)
#pragma unroll
    for (int ks = 0; ks < 2; ++ks)
      qf[qg][ks] = *(const bf16x8*)(qh + (size_t)(qbase + qg * 16 + l16) * HDIM + ks * 32 + quad * 8);

  float lsum[2] = {};
  f32x4 o[2][4] = {};
  f32x4 sc[2][4] = {};
  u16* pw = &Plds[wave][0];

  // stage key-tile kb (64 keys) into buffer bidx: 4 DMA instrs per wave
  auto stage = [&](int bidx, int kb) {
#pragma unroll
    for (int p = 0; p < 2; ++p) {
      const int i = wave * 2 + p;          // instr 0..7, wave-uniform
      async16(&Klds[bidx][i * 512], kh  + (size_t)(kb + i * 8 + r8) * HDIM + jsw * 8);
      async16(&Vlds[bidx][i * 512], vth + (size_t)(i * 8 + r8) * SEQ + kb + jsw * 8);
    }
  };
  // S^T = K * Q from buffer bidx into sc
  auto qkt = [&](int bidx) {
#pragma unroll
    for (int qg = 0; qg < 2; ++qg)
#pragma unroll
      for (int nt = 0; nt < 4; ++nt) sc[qg][nt] = f32x4{0.f, 0.f, 0.f, 0.f};
#pragma unroll
    for (int ks = 0; ks < 2; ++ks)
#pragma unroll
      for (int nt = 0; nt < 4; ++nt) {
        bf16x8 kf = *(const bf16x8*)&Klds[bidx][(nt * 16 + l16) * 64 + ((ks * 4 + quad) ^ e7) * 8];
#pragma unroll
        for (int qg = 0; qg < 2; ++qg)
          sc[qg][nt] = __builtin_amdgcn_mfma_f32_16x16x32_bf16(kf, qf[qg][ks], sc[qg][nt], 0, 0, 0);
      }
  };

  // ---- prologue: stage tiles 0,1; compute QK(0) ----
  stage(0, 0);
  stage(1, 64);
  asm volatile("s_waitcnt vmcnt(0)" ::: "memory");
  __syncthreads();
  qkt(0);

  int i0 = 0, i1 = 1, i2 = 2;   // rotating buffer indices: t, t+1, t+2
  for (int t = 0; t < 32; ++t) {
    if (t < 30) stage(i2, (t + 2) * 64);

    // ---- exp(t): p = exp2(s^T), packed ds_write_b64 into P[s][z] ----
    // lane holds S^T[z = nt*16+quad*4+r][s = qg*16+l16]; 8B slot = nt*4+quad,
    // swizzled slot' = slot ^ 2*(s&7)
#pragma unroll
    for (int qg = 0; qg < 2; ++qg) {
      float ls = 0.f;
#pragma unroll
      for (int nt = 0; nt < 4; ++nt) {
        const float p0 = __builtin_exp2f(sc[qg][nt][0]);
        const float p1 = __builtin_exp2f(sc[qg][nt][1]);
        const float p2 = __builtin_exp2f(sc[qg][nt][2]);
        const float p3 = __builtin_exp2f(sc[qg][nt][3]);
        ls += (p0 + p1) + (p2 + p3);
        uint2 pkv; pkv.x = pk2(p0, p1); pkv.y = pk2(p2, p3);
        *(uint2*)(pw + (qg * 16 + l16) * 64 + ((nt * 4 + quad) ^ psw) * 4) = pkv;
      }
      lsum[qg] += ls;
    }

    // ---- QK(t+1): independent MFMA work overlapping exp + P round-trip ----
    if (t < 31) qkt(i1);

    // ---- PV(t): O += P @ V ----
#pragma unroll
    for (int ks = 0; ks < 2; ++ks) {
      bf16x8 pf0 = *(const bf16x8*)&pw[(0 * 16 + l16) * 64 + ((ks * 8 + quad * 2) ^ psw) * 4];
      bf16x8 pf1 = *(const bf16x8*)&pw[(1 * 16 + l16) * 64 + ((ks * 8 + quad * 2) ^ psw) * 4];
#pragma unroll
      for (int dt = 0; dt < 4; ++dt) {
        bf16x8 vfr = *(const bf16x8*)&Vlds[i0][(dt * 16 + l16) * 64 + ((ks * 4 + quad) ^ e7) * 8];
        o[0][dt] = __builtin_amdgcn_mfma_f32_16x16x32_bf16(pf0, vfr, o[0][dt], 0, 0, 0);
        o[1][dt] = __builtin_amdgcn_mfma_f32_16x16x32_bf16(pf1, vfr, o[1][dt], 0, 0, 0);
      }
    }

    if (t < 31) {
      asm volatile("s_waitcnt vmcnt(0)" ::: "memory");  // own DMA(t+2) landed
      __syncthreads();                                  // all waves: t+2 visible
    }
    const int tmp = i0; i0 = i1; i1 = i2; i2 = tmp;
  }

  // ---- lsum: reduce across the 4 quads, broadcast via wave-private LDS ----
#pragma unroll
  for (int qg = 0; qg < 2; ++qg) {
    lsum[qg] += __shfl_xor(lsum[qg], 16, 64);
    lsum[qg] += __shfl_xor(lsum[qg], 32, 64);
  }
  asm volatile("s_waitcnt lgkmcnt(0)" ::: "memory");
  float* lw = (float*)pw;
  if (lane < 16) { lw[lane] = lsum[0]; lw[16 + lane] = lsum[1]; }
  asm volatile("s_waitcnt lgkmcnt(0)" ::: "memory");

#pragma unroll
  for (int qg = 0; qg < 2; ++qg) {
#pragma unroll
    for (int r = 0; r < 4; ++r) {
      const float inv = 1.f / fmaxf(lw[qg * 16 + quad * 4 + r], 1e-20f);
      const int s = qbase + qg * 16 + quad * 4 + r;
#pragma unroll
      for (int dt = 0; dt < 4; ++dt) {
        const int d = dt * 16 + l16;
        out[((size_t)(b * SEQ + s) * HEADS + h) * HDIM + d] = o[qg][dt][r] * inv;
      }
    }
  }
}

extern "C" void kernel_launch(void* const* d_in, const int* in_sizes, int n_in,
                              void* d_out, int out_size, void* d_ws, size_t ws_size,
                              hipStream_t stream) {
  (void)in_sizes; (void)n_in; (void)out_size; (void)ws_size;
  const float* x  = (const float*)d_in[0];
  const float* Wq = (const float*)d_in[1];
  const float* bq = (const float*)d_in[2];
  const float* Wk = (const float*)d_in[3];
  const float* bk = (const float*)d_in[4];
  const float* Wv = (const float*)d_in[5];
  const float* bv = (const float*)d_in[6];
  float* out = (float*)d_out;

  u16* ws = (u16*)d_ws;
  const size_t XSZ = (size_t)BATCH * SEQ * DIM;           // 4M elems
  const size_t WSZ = (size_t)DIM * DIM;                   // 1M elems
  const size_t QSZ = (size_t)BATCH * HEADS * SEQ * HDIM;  // 4M elems
  u16* xbf   = ws;                       // bf16 x       [m][k]
  u16* wbf   = ws + XSZ;                 // bf16 Wq|Wk|Wv [n][k]
  u16* qbuf  = ws + XSZ + 3 * WSZ;       // bf16 Q(*QSCALE) [b][h][s][d]
  u16* kbuf  = qbuf + QSZ;               // bf16 K   [b][h][s][d]
  u16* vtbuf = kbuf + QSZ;               // bf16 V^T [b][h][d][s]

  convert_all<<<3584, 256, 0, stream>>>(x, Wq, Wk, Wv, xbf, wbf);

  dim3 g1(DIM / 128, (BATCH * SEQ) / 128, 3);   // 8 x 32 x 3 = 768 blocks
  qkv_gemm<<<g1, 256, 0, stream>>>(xbf, wbf, bq, bk, bv, qbuf, kbuf, vtbuf);

  dim3 g2(SEQ / 128, HEADS, BATCH);             // 16 x 16 x 2 = 512 blocks
  attn<<<g2, 256, 0, stream>>>(qbuf, kbuf, vtbuf, out);
}

// Round 10
// 180.310 us; speedup vs baseline: 1.1832x; 1.1832x over previous
//
#include <hip/hip_runtime.h>
#include <hip/hip_bf16.h>

typedef unsigned short u16;
typedef __attribute__((ext_vector_type(8))) __bf16 bf16x8;
typedef __attribute__((ext_vector_type(4))) float f32x4;
typedef __attribute__((ext_vector_type(8))) u16 u16x8;

#define BATCH 2
#define SEQ   2048
#define DIM   1024
#define HEADS 16
#define HDIM  64

// 0.125 (1/sqrt(64)) * log2(e): folded into Q so attn uses bare exp2
#define QSCALE 0.18033688011112042f

__device__ __forceinline__ float bf2f(u16 u) {
  union { unsigned int u; float f; } v; v.u = ((unsigned int)u) << 16; return v.f;
}
__device__ __forceinline__ u16 f2bf(float f) {
  union { float f; unsigned int u; } v; v.f = f;
  unsigned int r = v.u + 0x7fffu + ((v.u >> 16) & 1u);
  return (u16)(r >> 16);
}
// pack two fp32 -> bf16x2 (RNE) in one HW instr (v_cvt_pk_bf16_f32)
__device__ __forceinline__ unsigned int pk2(float a, float b) {
  union { __hip_bfloat162 h2; unsigned int u; } v;
  v.h2 = __float22bfloat162_rn(float2{a, b});
  return v.u;
}

// async global->LDS DMA, 16 B per lane; LDS dest = wave-uniform base + lane*16
__device__ __forceinline__ void async16(u16* lds, const u16* g) {
  __builtin_amdgcn_global_load_lds(
      (__attribute__((address_space(1))) void*)(void*)(g),
      (__attribute__((address_space(3))) void*)(lds), 16, 0, 0);
}

// ---------------------------------------------------------------------------
// Kernel 0: one-shot fp32 -> bf16 (RNE) conversion of x, Wq, Wk, Wv.
// ---------------------------------------------------------------------------
#define XG  524288   /* x groups of 8 */
#define WG  131072   /* per-W groups of 8 */
extern "C" __global__ __launch_bounds__(256)
void convert_all(const float* __restrict__ x,  const float* __restrict__ wq,
                 const float* __restrict__ wk, const float* __restrict__ wv,
                 u16* __restrict__ xbf, u16* __restrict__ wbf)
{
  const int g = blockIdx.x * 256 + threadIdx.x;
  const float* src; u16* dst; size_t off;
  if (g < XG)               { src = x;  dst = xbf;                 off = (size_t)g; }
  else if (g < XG + WG)     { src = wq; dst = wbf;                 off = (size_t)(g - XG); }
  else if (g < XG + 2 * WG) { src = wk; dst = wbf + DIM * DIM;     off = (size_t)(g - XG - WG); }
  else                      { src = wv; dst = wbf + 2 * DIM * DIM; off = (size_t)(g - XG - 2 * WG); }
  f32x4 a = *(const f32x4*)(src + off * 8);
  f32x4 b = *(const f32x4*)(src + off * 8 + 4);
  u16x8 o;
#pragma unroll
  for (int i = 0; i < 4; ++i) { o[i] = f2bf(a[i]); o[4 + i] = f2bf(b[i]); }
  *(u16x8*)(dst + off * 8) = o;
}

// ---------------------------------------------------------------------------
// Kernel 1: QKV projection — round-7 version (measured 95 us; BK=64 and
// explicit dbuf both regressed). 128x128 tile, BK=32, sync global_load_lds
// staging, 4 waves x 4x4 MFMA. grid: (8, 32, 3)  block: 256
// which==0 -> Q(*QSCALE) [b][h][s][d]; 1 -> K [b][h][s][d]; 2 -> V^T [b][h][d][s]
// ---------------------------------------------------------------------------
extern "C" __global__ __launch_bounds__(256)
void qkv_gemm(const u16* __restrict__ xbf, const u16* __restrict__ wbf,
              const float* __restrict__ bq, const float* __restrict__ bk,
              const float* __restrict__ bv,
              u16* __restrict__ qo, u16* __restrict__ ko, u16* __restrict__ vto)
{
  __shared__ alignas(16) u16 Albs[128 * 32];  // 8 KB
  __shared__ alignas(16) u16 Blbs[128 * 32];  // 8 KB

  const int which = blockIdx.z;
  const u16* Wb = wbf + (size_t)which * DIM * DIM;
  const float* bias = (which == 0) ? bq : (which == 1) ? bk : bv;

  const int lane = threadIdx.x & 63;
  const int wave = threadIdx.x >> 6;
  const int l16  = lane & 15;
  const int quad = lane >> 4;
  const int lrow = lane >> 2;        // 16 rows per DMA instr
  const int lcol = (lane & 3) * 8;   // 4 lanes per 32-elem row

  const int mBase = blockIdx.y * 128;
  const int nBase = blockIdx.x * 128;
  const int mw = (wave >> 1) * 64;   // wave's 64x64 quadrant
  const int nw = (wave & 1) * 64;

  f32x4 acc[4][4] = {};

  for (int k0 = 0; k0 < DIM; k0 += 32) {
#pragma unroll
    for (int p = 0; p < 2; ++p) {
      const int r16 = wave * 2 + p;                  // wave-uniform
      const int row = r16 * 16 + lrow;
      async16(&Albs[r16 * 512], xbf + (size_t)(mBase + row) * DIM + k0 + lcol);
      async16(&Blbs[r16 * 512], Wb  + (size_t)(nBase + row) * DIM + k0 + lcol);
    }
    asm volatile("s_waitcnt vmcnt(0)" ::: "memory");
    __syncthreads();

    bf16x8 af[4], bfr[4];
#pragma unroll
    for (int i = 0; i < 4; ++i) {
      af[i]  = *(const bf16x8*)&Albs[(mw + i * 16 + l16) * 32 + quad * 8];
      bfr[i] = *(const bf16x8*)&Blbs[(nw + i * 16 + l16) * 32 + quad * 8];
    }
#pragma unroll
    for (int mi = 0; mi < 4; ++mi)
#pragma unroll
      for (int ni = 0; ni < 4; ++ni)
        acc[mi][ni] = __builtin_amdgcn_mfma_f32_16x16x32_bf16(af[mi], bfr[ni], acc[mi][ni], 0, 0, 0);
    __syncthreads();
  }

  const float oscale = (which == 0) ? QSCALE : 1.0f;
#pragma unroll
  for (int ni = 0; ni < 4; ++ni) {
    const int n = nBase + nw + ni * 16 + l16;   // C/D col = lane&15
    const float bval = bias[n];
    const int h = n >> 6, d = n & 63;
#pragma unroll
    for (int mi = 0; mi < 4; ++mi) {
#pragma unroll
      for (int r = 0; r < 4; ++r) {
        const int m = mBase + mw + mi * 16 + quad * 4 + r;  // row = quad*4+reg
        const int bi = m >> 11, s = m & 2047;
        const u16 val = f2bf((acc[mi][ni][r] + bval) * oscale);
        if (which == 2) {
          vto[((size_t)(bi * HEADS + h) * HDIM + d) * SEQ + s] = val;
        } else {
          u16* dst = (which == 0) ? qo : ko;
          dst[((size_t)(bi * HEADS + h) * SEQ + s) * HDIM + d] = val;
        }
      }
    }
  }
}

// ---------------------------------------------------------------------------
// Kernel 2: flash attention per (b, h), pipelined across key tiles.
// Triple-buffered K/V, prefetch distance 2, CORRECT bottom wait vmcnt(4)
// (r9's vmcnt(0) drained the just-issued t+2 DMAs - pipeline was dead).
// Per iter: exp(t) -> QK(t+1) -> PV(t).
// exp via __builtin_amdgcn_exp2f (raw v_exp_f32; scores bounded, no range
// fixup needed - __builtin_exp2f lowers to the range-checked ocml call).
// P tile: pitch 64 u16, 8B-slot swizzle slot' = slot ^ l16 (full 4-bit key):
// per quarter-wave all 16 slots distinct -> all 32 banks -> conflict-free
// writes AND reads; reads become 2x ds_read_b64 (odd XOR breaks 16B pairs).
// grid: (SEQ/128, HEADS, BATCH) = (16,16,2)  block: 256
// ---------------------------------------------------------------------------
extern "C" __global__ __launch_bounds__(256)
void attn(const u16* __restrict__ q, const u16* __restrict__ k,
          const u16* __restrict__ vt, float* __restrict__ out)
{
  __shared__ alignas(16) u16 Klds[3][64 * 64];
  __shared__ alignas(16) u16 Vlds[3][64 * 64];
  __shared__ alignas(16) u16 Plds[4][32 * 64];

  const int lane = threadIdx.x & 63;
  const int wave = threadIdx.x >> 6;
  const int l16  = lane & 15;
  const int quad = lane >> 4;
  const int r8   = lane >> 3;       // DMA: row within 8-row group
  const int sl   = lane & 7;        // DMA: 16B slot within row
  const int jsw  = sl ^ (r8 & 7);   // swizzled source chunk for DMA
  const int e7   = l16 & 7;         // 16B-chunk swizzle key (K/V reads)

  const int h     = blockIdx.y;
  const int b     = blockIdx.z;
  const int qbase = blockIdx.x * 128 + wave * 32;

  const u16* qh  = q  + (size_t)(b * HEADS + h) * SEQ * HDIM;
  const u16* kh  = k  + (size_t)(b * HEADS + h) * SEQ * HDIM;
  const u16* vth = vt + (size_t)(b * HEADS + h) * HDIM * SEQ;

  // Q B-frags: lane l16 -> q-row qbase+qg*16+l16, k = ks*32+quad*8..+7
  bf16x8 qf[2][2];
#pragma unroll
  for (int qg = 0; qg < 2; ++qg)
#pragma unroll
    for (int ks = 0; ks < 2; ++ks)
      qf[qg][ks] = *(const bf16x8*)(qh + (size_t)(qbase + qg * 16 + l16) * HDIM + ks * 32 + quad * 8);

  float lsum[2] = {};
  f32x4 o[2][4] = {};
  f32x4 sc[2][4] = {};
  u16* pw = &Plds[wave][0];

  // stage key-tile kb (64 keys) into buffer bidx: 4 DMA instrs per wave
  auto stage = [&](int bidx, int kb) {
#pragma unroll
    for (int p = 0; p < 2; ++p) {
      const int i = wave * 2 + p;          // instr 0..7, wave-uniform
      async16(&Klds[bidx][i * 512], kh  + (size_t)(kb + i * 8 + r8) * HDIM + jsw * 8);
      async16(&Vlds[bidx][i * 512], vth + (size_t)(i * 8 + r8) * SEQ + kb + jsw * 8);
    }
  };
  // S^T = K * Q from buffer bidx into sc
  auto qkt = [&](int bidx) {
#pragma unroll
    for (int qg = 0; qg < 2; ++qg)
#pragma unroll
      for (int nt = 0; nt < 4; ++nt) sc[qg][nt] = f32x4{0.f, 0.f, 0.f, 0.f};
#pragma unroll
    for (int ks = 0; ks < 2; ++ks)
#pragma unroll
      for (int nt = 0; nt < 4; ++nt) {
        bf16x8 kf = *(const bf16x8*)&Klds[bidx][(nt * 16 + l16) * 64 + ((ks * 4 + quad) ^ e7) * 8];
#pragma unroll
        for (int qg = 0; qg < 2; ++qg)
          sc[qg][nt] = __builtin_amdgcn_mfma_f32_16x16x32_bf16(kf, qf[qg][ks], sc[qg][nt], 0, 0, 0);
      }
  };

  // ---- prologue: stage tiles 0,1; wait tile 0 only; compute QK(0) ----
  stage(0, 0);
  stage(1, 64);
  asm volatile("s_waitcnt vmcnt(4)" ::: "memory");  // tile 0 landed, tile 1 in flight
  __syncthreads();
  qkt(0);

  int i0 = 0, i1 = 1, i2 = 2;   // rotating buffer indices: t, t+1, t+2
  for (int t = 0; t < 32; ++t) {
    if (t < 30) stage(i2, (t + 2) * 64);

    // ---- exp(t): p = exp2(s^T), packed ds_write_b64 into P[s][slot^l16] ----
    // lane holds S^T[z = nt*16+quad*4+r][s = qg*16+l16]; 8B slot = nt*4+quad
#pragma unroll
    for (int qg = 0; qg < 2; ++qg) {
      float ls = 0.f;
#pragma unroll
      for (int nt = 0; nt < 4; ++nt) {
        const float p0 = __builtin_amdgcn_exp2f(sc[qg][nt][0]);
        const float p1 = __builtin_amdgcn_exp2f(sc[qg][nt][1]);
        const float p2 = __builtin_amdgcn_exp2f(sc[qg][nt][2]);
        const float p3 = __builtin_amdgcn_exp2f(sc[qg][nt][3]);
        ls += (p0 + p1) + (p2 + p3);
        uint2 pkv; pkv.x = pk2(p0, p1); pkv.y = pk2(p2, p3);
        *(uint2*)(pw + (qg * 16 + l16) * 64 + (((nt * 4 + quad) ^ l16) * 4)) = pkv;
      }
      lsum[qg] += ls;
    }

    // ---- QK(t+1): independent MFMA work overlapping exp + P round-trip ----
    if (t < 31) qkt(i1);

    // ---- PV(t): O += P @ V ----
#pragma unroll
    for (int ks = 0; ks < 2; ++ks) {
      bf16x8 pf[2];
#pragma unroll
      for (int qg = 0; qg < 2; ++qg) {
        const int rowo = (qg * 16 + l16) * 64;
        const int s0 = ks * 8 + quad * 2;
        uint2 lo = *(const uint2*)(pw + rowo + ((s0    ) ^ l16) * 4);
        uint2 hi = *(const uint2*)(pw + rowo + ((s0 + 1) ^ l16) * 4);
        union { uint4 u; bf16x8 v; } cvt;
        cvt.u = uint4{lo.x, lo.y, hi.x, hi.y};
        pf[qg] = cvt.v;
      }
#pragma unroll
      for (int dt = 0; dt < 4; ++dt) {
        bf16x8 vfr = *(const bf16x8*)&Vlds[i0][(dt * 16 + l16) * 64 + ((ks * 4 + quad) ^ e7) * 8];
        o[0][dt] = __builtin_amdgcn_mfma_f32_16x16x32_bf16(pf[0], vfr, o[0][dt], 0, 0, 0);
        o[1][dt] = __builtin_amdgcn_mfma_f32_16x16x32_bf16(pf[1], vfr, o[1][dt], 0, 0, 0);
      }
    }

    // bottom wait: drain tile t+1 (next to read), keep t+2's 4 DMAs in flight
    if (t < 30)      asm volatile("s_waitcnt vmcnt(4)" ::: "memory");
    else if (t < 31) asm volatile("s_waitcnt vmcnt(0)" ::: "memory");
    if (t < 31) __syncthreads();
    const int tmp = i0; i0 = i1; i1 = i2; i2 = tmp;
  }

  // ---- lsum: reduce across the 4 quads, broadcast via wave-private LDS ----
#pragma unroll
  for (int qg = 0; qg < 2; ++qg) {
    lsum[qg] += __shfl_xor(lsum[qg], 16, 64);
    lsum[qg] += __shfl_xor(lsum[qg], 32, 64);
  }
  asm volatile("s_waitcnt lgkmcnt(0)" ::: "memory");
  float* lw = (float*)pw;
  if (lane < 16) { lw[lane] = lsum[0]; lw[16 + lane] = lsum[1]; }
  asm volatile("s_waitcnt lgkmcnt(0)" ::: "memory");

#pragma unroll
  for (int qg = 0; qg < 2; ++qg) {
#pragma unroll
    for (int r = 0; r < 4; ++r) {
      const float inv = 1.f / fmaxf(lw[qg * 16 + quad * 4 + r], 1e-20f);
      const int s = qbase + qg * 16 + quad * 4 + r;
#pragma unroll
      for (int dt = 0; dt < 4; ++dt) {
        const int d = dt * 16 + l16;
        out[((size_t)(b * SEQ + s) * HEADS + h) * HDIM + d] = o[qg][dt][r] * inv;
      }
    }
  }
}

extern "C" void kernel_launch(void* const* d_in, const int* in_sizes, int n_in,
                              void* d_out, int out_size, void* d_ws, size_t ws_size,
                              hipStream_t stream) {
  (void)in_sizes; (void)n_in; (void)out_size; (void)ws_size;
  const float* x  = (const float*)d_in[0];
  const float* Wq = (const float*)d_in[1];
  const float* bq = (const float*)d_in[2];
  const float* Wk = (const float*)d_in[3];
  const float* bk = (const float*)d_in[4];
  const float* Wv = (const float*)d_in[5];
  const float* bv = (const float*)d_in[6];
  float* out = (float*)d_out;

  u16* ws = (u16*)d_ws;
  const size_t XSZ = (size_t)BATCH * SEQ * DIM;           // 4M elems
  const size_t WSZ = (size_t)DIM * DIM;                   // 1M elems
  const size_t QSZ = (size_t)BATCH * HEADS * SEQ * HDIM;  // 4M elems
  u16* xbf   = ws;                       // bf16 x       [m][k]
  u16* wbf   = ws + XSZ;                 // bf16 Wq|Wk|Wv [n][k]
  u16* qbuf  = ws + XSZ + 3 * WSZ;       // bf16 Q(*QSCALE) [b][h][s][d]
  u16* kbuf  = qbuf + QSZ;               // bf16 K   [b][h][s][d]
  u16* vtbuf = kbuf + QSZ;               // bf16 V^T [b][h][d][s]

  convert_all<<<3584, 256, 0, stream>>>(x, Wq, Wk, Wv, xbf, wbf);

  dim3 g1(DIM / 128, (BATCH * SEQ) / 128, 3);   // 8 x 32 x 3 = 768 blocks
  qkv_gemm<<<g1, 256, 0, stream>>>(xbf, wbf, bq, bk, bv, qbuf, kbuf, vtbuf);

  dim3 g2(SEQ / 128, HEADS, BATCH);             // 16 x 16 x 2 = 512 blocks
  attn<<<g2, 256, 0, stream>>>(qbuf, kbuf, vtbuf, out);
}